// Round 21
// baseline (6305.968 us; speedup 1.0000x reference)
//
#include <hip/hip_runtime.h>
#include <stdint.h>

typedef unsigned long long u64;

#define VOCAB 128
#define RD 128
#define DM 1024
#define NFF 6
#define BATCH 64
#define TSTEPS 512
#define THR 512

// ---------------------------------------------------------------------------
// ws layout (bytes):
//   [0, 786432)    ffs: 24 contiguous 32 KB stage blocks.
//                  stage S = L*4 + half*2 + kh  (L<6, half<2, kh<2)
//                  u64 idx = S*4096 + qq*1024 + c*2 + s
//                  (qq<4: local word-pair, global pair q = kh*4+qq;
//                   c<512: column within half; s: word within pair)
//                  Linear DMA of a stage delivers LDS pair qq of col c at
//                  byte qq*8192 + c*16 -> conflict-free b128 reads.
//   [786432, +2048)   ebits [v][2] u64
//   [788480, +2048)   headb [v][2] u64
//   [790528, +512)    losses [64] double
// ---------------------------------------------------------------------------
#define OFF_EB    786432
#define OFF_HB    788480
#define OFF_LOSS  790528

typedef const __attribute__((address_space(1))) void* gas1_t;
typedef __attribute__((address_space(3))) void*       las3_t;

// Pack ff sign bits. bit b of word (L,w,j) = (ff[L][w*64+b][j] < 0)  (1 => -1)
__global__ void pack_ff(const float* __restrict__ ff, u64* __restrict__ ffs) {
    int wid  = blockIdx.x * (blockDim.x >> 6) + (threadIdx.x >> 6); // 0..1535
    int lane = threadIdx.x & 63;
    int jt = wid & 15;
    int w  = (wid >> 4) & 15;  // word 0..15
    int L  = wid >> 8;         // layer
    int j  = jt * 64 + lane;   // column
    const float* src = ff + ((size_t)(L * DM) + w * 64) * DM + j;
    u64 word = 0;
#pragma unroll
    for (int b = 0; b < 64; ++b) {
        float v = src[(size_t)b * DM];
        word |= (u64)(v < 0.0f) << b;
    }
    int q = w >> 1, s = w & 1;
    int half = j >> 9, c = j & 511;
    int kh = q >> 2, qq = q & 3;
    int stage = L * 4 + half * 2 + kh;
    ffs[(size_t)stage * 4096 + qq * 1024 + c * 2 + s] = word;
}

// Pack embed rows and head columns (tiny).
__global__ void pack_small(const float* __restrict__ emb, const float* __restrict__ head,
                           u64* __restrict__ eb, u64* __restrict__ hb) {
    int tid = threadIdx.x; // 0..255
    if (tid < 128) {
        int v = tid;
        for (int wd = 0; wd < 2; ++wd) {
            u64 word = 0;
            for (int l = 0; l < 64; ++l)
                word |= (u64)(emb[v * RD + wd * 64 + l] < 0.0f) << l;
            eb[v * 2 + wd] = word;
        }
    } else {
        int v = tid - 128;
        for (int wd = 0; wd < 2; ++wd) {
            u64 word = 0;
            for (int l = 0; l < 64; ++l)
                word |= (u64)(head[(wd * 64 + l) * VOCAB + v] < 0.0f) << l;
            hb[v * 2 + wd] = word;
        }
    }
}

// Issue stage S (32 KB) into ring buffer B via global_load_lds:
// 4 insts/wave x 1 KB; LDS base wave-uniform (HW adds lane*16 both sides).
#define ISSUE(S, B)                                                            \
    do {                                                                       \
        const u64* gp_ = ffs + ((S) * 4096) + (wv << 9) + (lane << 1);         \
        u64* lp_ = sbuf + ((B) * 4096) + (wv << 9);                            \
        _Pragma("unroll")                                                      \
        for (int k_ = 0; k_ < 4; ++k_) {                                       \
            __builtin_amdgcn_global_load_lds((gas1_t)(gp_ + (k_ << 7)),        \
                                             (las3_t)(lp_ + (k_ << 7)), 16, 0, 0); \
        }                                                                      \
    } while (0)

// Stage body s: issue s+2 (2-deep), compute s (4 weight pairs, partial acc),
// ballot on kh==1, then COUNTED wait: vmcnt(4) = my s+1 loads done, s+2's 4
// still in flight (never drain to 0 in the loop). Raw s_barrier (no implicit
// vmem drain).
#define STG(S)                                                                 \
    do {                                                                       \
        ISSUE((((S) + 2) % 24), (((S) + 2) % 3));                              \
        {                                                                      \
            const int L_ = (S) >> 2, HALF_ = ((S) >> 1) & 1, KH_ = (S) & 1;    \
            const ulonglong2* hp_ = (const ulonglong2*)hx[L_ & 1];             \
            const u64* wb_ = sbuf + (((S) % 3) * 4096) + (tid << 1);           \
            _Pragma("unroll")                                                  \
            for (int qq_ = 0; qq_ < 4; ++qq_) {                                \
                ulonglong2 hv_ = hp_[KH_ * 4 + qq_]; /* broadcast b128 */      \
                ulonglong2 wq_ = *(const ulonglong2*)(wb_ + (qq_ << 10));      \
                acc += __popcll(hv_.x ^ wq_.x) + __popcll(hv_.y ^ wq_.y);      \
            }                                                                  \
            if (KH_) {                                                         \
                u64 m_ = __ballot(acc >= cthr[L_][HALF_]);                     \
                if (lane == 0) hx[(L_ + 1) & 1][HALF_ * 8 + wv] = m_;          \
                acc = 0;                                                       \
            }                                                                  \
        }                                                                      \
        asm volatile("s_waitcnt vmcnt(4) lgkmcnt(0)" ::: "memory");            \
        __builtin_amdgcn_s_barrier();                                          \
    } while (0)

// lgkm-only barrier (head/splice phase; stage 0'/1' DMAs stay in flight)
#define BARRIER()                                                              \
    do {                                                                       \
        asm volatile("s_waitcnt lgkmcnt(0)" ::: "memory");                     \
        __builtin_amdgcn_s_barrier();                                          \
    } while (0)

// Main recurrent kernel: one block (one CU) per batch row, 512 threads.
// All 6 layers stream L2 -> LDS through a 3 x 32 KB ring with a 2-deep
// counted-vmcnt DMA pipeline: delivery of stage s+1 overlaps the full
// compute of stage s AND the issue window of s+2. ~56 VGPRs: no spill.
__global__ void __launch_bounds__(THR)
brnn_main(const int* __restrict__ tokens,
          const float* __restrict__ initial_lat,
          const float* __restrict__ thr_lat,
          const u64* __restrict__ ffs,
          const u64* __restrict__ eb,
          const u64* __restrict__ hb,
          double* __restrict__ losses)
{
    const int b    = blockIdx.x;
    const int tid  = threadIdx.x;
    const int lane = tid & 63;
    const int wv   = tid >> 6;   // 0..7

    __shared__ __align__(16) u64 sbuf[3 * 4096];  // 3 x 32 KB staging ring
    __shared__ __align__(16) u64 hx[2][16];
    __shared__ u64 hbL[2 * VOCAB];

    if (tid < 2 * VOCAB) hbL[tid] = hb[tid];

    // thresholds: thread handles col half*512+tid of each layer
    int cthr[NFF][2];
#pragma unroll
    for (int L = 0; L < NFF; ++L)
#pragma unroll
        for (int h2 = 0; h2 < 2; ++h2) {
            int th = (int)rintf(thr_lat[L * DM + h2 * 512 + tid]); // round-half-even
            cthr[L][h2] = ((DM - th) >> 1) + 1;
        }

    // init h = sign(initial_lat) into hx[0]
    {
        u64 m0 = __ballot(initial_lat[tid] < 0.0f);
        u64 m1 = __ballot(initial_lat[512 + tid] < 0.0f);
        if (lane == 0) { hx[0][wv] = m0; hx[0][8 + wv] = m1; }
    }

    // prologue: stages 0,1 in flight; wait only for stage 0 (vmcnt(4))
    ISSUE(0, 0);
    ISSUE(1, 1);
    asm volatile("s_waitcnt vmcnt(4) lgkmcnt(0)" ::: "memory");
    __builtin_amdgcn_s_barrier();

    const int* toks = tokens + b * TSTEPS;
    double lacc = 0.0;
    int acc = 0;

    for (int t = 0; t < TSTEPS; ++t) {
        const int tok = toks[t]; // uniform -> scalar load
        u64 enew = 0;
        if (wv == 0 && lane < 2) enew = eb[tok * 2 + lane]; // prefetch for splice

        // --- 24 stages (6 layers x 2 halves x 2 K-halves), 2-deep pipeline ---
        STG(0);  STG(1);  STG(2);  STG(3);
        STG(4);  STG(5);  STG(6);  STG(7);
        STG(8);  STG(9);  STG(10); STG(11);
        STG(12); STG(13); STG(14); STG(15);
        STG(16); STG(17); STG(18); STG(19);
        STG(20); STG(21); STG(22); STG(23);
        // (stages 22,23 issued next step's stages 0,1)

        // --- head + log-softmax + loss + embed splice (wave 0); h5 in hx[0] ---
        if (wv == 0) {
            u64 ra = hx[0][14], rb = hx[0][15];
            u64 h0a = hbL[lane * 2 + 0],        h0b = hbL[lane * 2 + 1];
            u64 h1a = hbL[(lane + 64) * 2 + 0], h1b = hbL[(lane + 64) * 2 + 1];
            int d0 = 128 - 2 * (__popcll(ra ^ h0a) + __popcll(rb ^ h0b));
            int d1 = 128 - 2 * (__popcll(ra ^ h1a) + __popcll(rb ^ h1b));
            float l0 = (float)d0 * (1.0f / 16.0f);
            float l1 = (float)d1 * (1.0f / 16.0f);
            float mx = fmaxf(l0, l1);
#pragma unroll
            for (int sh = 32; sh >= 1; sh >>= 1) mx = fmaxf(mx, __shfl_xor(mx, sh));
            float se = __expf(l0 - mx) + __expf(l1 - mx);
#pragma unroll
            for (int sh = 32; sh >= 1; sh >>= 1) se += __shfl_xor(se, sh);
            int   tl   = tok & 63;
            float la   = __shfl(l0, tl);
            float lb   = __shfl(l1, tl);
            float ltok = (tok >> 6) ? lb : la;
            lacc += (double)(mx + __logf(se) - ltok);
            // splice x_new read-part = sign(embed[tok]) into words 14,15
            if (lane < 2) hx[0][14 + lane] = enew;
        }
        BARRIER();
    }

    asm volatile("s_waitcnt vmcnt(0)" ::: "memory"); // drain leftover prefetch
    if (tid == 0) losses[b] = lacc;
}

__global__ void reduce_loss(const double* __restrict__ losses, float* __restrict__ out) {
    int lane = threadIdx.x; // 64 threads, 1 wave
    double v = losses[lane];
#pragma unroll
    for (int sh = 32; sh >= 1; sh >>= 1) v += __shfl_down(v, sh);
    if (lane == 0) out[0] = (float)(v * (1.0 / ((double)BATCH * (double)TSTEPS)));
}

extern "C" void kernel_launch(void* const* d_in, const int* in_sizes, int n_in,
                              void* d_out, int out_size, void* d_ws, size_t ws_size,
                              hipStream_t stream) {
    const int*   tokens  = (const int*)d_in[0];   // (64, 512) int32
    const float* initial = (const float*)d_in[1]; // (1024,)
    const float* embed   = (const float*)d_in[2]; // (128, 128)
    const float* ff      = (const float*)d_in[3]; // (6, 1024, 1024)
    const float* head    = (const float*)d_in[4]; // (128, 128)
    const float* thrl    = (const float*)d_in[5]; // (6, 1024)

    char* ws = (char*)d_ws;
    u64*    ffs    = (u64*)ws;                 // 786432 B
    u64*    eb     = (u64*)(ws + OFF_EB);      // 2048 B
    u64*    hb     = (u64*)(ws + OFF_HB);      // 2048 B
    double* losses = (double*)(ws + OFF_LOSS); // 512 B

    pack_ff<<<384, 256, 0, stream>>>(ff, ffs);
    pack_small<<<1, 256, 0, stream>>>(embed, head, eb, hb);
    brnn_main<<<BATCH, THR, 0, stream>>>(tokens, initial, thrl, ffs, eb, hb, losses);
    reduce_loss<<<1, 64, 0, stream>>>(losses, (float*)d_out);
}